// Round 1
// baseline (2545.813 us; speedup 1.0000x reference)
//
#include <hip/hip_runtime.h>
#include <math.h>

#define BT_TOTAL 65536
#define DIN 512
#define DEMB 256
#define KC 1024

// ---------------- kernel 1: codebook row norms + zero loss outputs ----------
__global__ __launch_bounds__(256) void cnorm_kernel(const float* __restrict__ cbook,
                                                    float* __restrict__ cnorm,
                                                    float* __restrict__ out_loss) {
    const int k = blockIdx.x;
    const int tid = threadIdx.x;
    float v = cbook[k * DEMB + tid];
    v *= v;
#pragma unroll
    for (int o = 32; o > 0; o >>= 1) v += __shfl_down(v, o);
    __shared__ float ps[4];
    if ((tid & 63) == 0) ps[tid >> 6] = v;
    __syncthreads();
    if (tid == 0) cnorm[k] = ps[0] + ps[1] + ps[2] + ps[3];
    if (k == 0 && tid < 32) out_loss[tid] = 0.0f;
}

// ---------------- row-dot GEMM: C[M,NSTR-block] = A[M,KD] * Bt[N,KD]^T ------
// 64x64 tile, BK=32, 256 threads as 16x16, 4x4 micro-tile, float4 LDS reads.
template <int KD, int NSTR>
__global__ __launch_bounds__(256) void gemm_rowdot(const float* __restrict__ A,
                                                   const float* __restrict__ Bt,
                                                   float* __restrict__ C) {
    __shared__ __align__(16) float As[64][36];  // pad 36 -> 2-way max conflicts
    __shared__ __align__(16) float Bs[64][36];
    const int tid = threadIdx.x;
    const int tx = tid & 15, ty = tid >> 4;
    const int rowBase = blockIdx.x * 64;
    const int colBase = blockIdx.y * 64;
    const int lr = tid >> 2;         // staging row 0..63
    const int lk = (tid & 3) * 8;    // staging k offset 0/8/16/24
    float acc[4][4] = {};
    for (int k0 = 0; k0 < KD; k0 += 32) {
        const float4 a0 = *(const float4*)(A + (size_t)(rowBase + lr) * KD + k0 + lk);
        const float4 a1 = *(const float4*)(A + (size_t)(rowBase + lr) * KD + k0 + lk + 4);
        const float4 b0 = *(const float4*)(Bt + (size_t)(colBase + lr) * KD + k0 + lk);
        const float4 b1 = *(const float4*)(Bt + (size_t)(colBase + lr) * KD + k0 + lk + 4);
        __syncthreads();
        *(float4*)&As[lr][lk] = a0;
        *(float4*)&As[lr][lk + 4] = a1;
        *(float4*)&Bs[lr][lk] = b0;
        *(float4*)&Bs[lr][lk + 4] = b1;
        __syncthreads();
#pragma unroll
        for (int e = 0; e < 32; e += 4) {
            float4 va[4], vb[4];
#pragma unroll
            for (int i = 0; i < 4; ++i) va[i] = *(const float4*)&As[4 * ty + i][e];
#pragma unroll
            for (int j = 0; j < 4; ++j) vb[j] = *(const float4*)&Bs[4 * tx + j][e];
#pragma unroll
            for (int i = 0; i < 4; ++i)
#pragma unroll
                for (int j = 0; j < 4; ++j) {
                    acc[i][j] = fmaf(va[i].x, vb[j].x, acc[i][j]);
                    acc[i][j] = fmaf(va[i].y, vb[j].y, acc[i][j]);
                    acc[i][j] = fmaf(va[i].z, vb[j].z, acc[i][j]);
                    acc[i][j] = fmaf(va[i].w, vb[j].w, acc[i][j]);
                }
        }
    }
#pragma unroll
    for (int i = 0; i < 4; ++i) {
        float4 o = make_float4(acc[i][0], acc[i][1], acc[i][2], acc[i][3]);
        *(float4*)(C + (size_t)(rowBase + 4 * ty + i) * NSTR + colBase + 4 * tx) = o;
    }
}

// ---------------- kernel 3: fused dist + argmin + losses --------------------
// One block per 64 rows of z_e_down; z tile LDS-resident, codebook streamed.
__global__ __launch_bounds__(256) void dist_argmin_kernel(
    const float* __restrict__ zed,       // [BT,256]
    const float* __restrict__ cbook,     // [1024,256]
    const float* __restrict__ cnorm,     // [1024]
    float* __restrict__ out_code,        // [BT] (float-encoded index)
    float* __restrict__ out_loss) {      // [32]: commit[16] then cb[16]
    __shared__ __align__(16) float zs[64][260];  // 66.5 KB, pad 260 -> 2-way max
    __shared__ __align__(16) float buf[2304];    // cs[64][36] / reduce arrays
    __shared__ int kbest[64];
    __shared__ float blockSum;
    float(*cs)[36] = (float(*)[36])buf;
    const int tid = threadIdx.x;
    const int tx = tid & 15, ty = tid >> 4;
    const int rowBase = blockIdx.x * 64;

    // stage 64 full z rows (coalesced: wave covers one row of 1 KB)
#pragma unroll
    for (int it = 0; it < 16; ++it) {
        const int r = it * 4 + (tid >> 6);
        const int e4 = (tid & 63) * 4;
        *(float4*)&zs[r][e4] = *(const float4*)(zed + (size_t)(rowBase + r) * 256 + e4);
    }

    float bestv[4] = {INFINITY, INFINITY, INFINITY, INFINITY};
    int besti[4] = {0, 0, 0, 0};

    for (int kc = 0; kc < KC; kc += 64) {
        float acc[4][4] = {};
        for (int e0 = 0; e0 < 256; e0 += 32) {
            const int c = tid >> 2;
            const int ep = (tid & 3) * 8;
            const float4 c0 = *(const float4*)(cbook + (size_t)(kc + c) * 256 + e0 + ep);
            const float4 c1 = *(const float4*)(cbook + (size_t)(kc + c) * 256 + e0 + ep + 4);
            __syncthreads();  // also covers initial zs staging on first iter
            *(float4*)&cs[c][ep] = c0;
            *(float4*)&cs[c][ep + 4] = c1;
            __syncthreads();
#pragma unroll
            for (int e = 0; e < 32; e += 4) {
                float4 va[4], vb[4];
#pragma unroll
                for (int i = 0; i < 4; ++i) va[i] = *(const float4*)&zs[4 * ty + i][e0 + e];
#pragma unroll
                for (int j = 0; j < 4; ++j) vb[j] = *(const float4*)&cs[4 * tx + j][e];
#pragma unroll
                for (int i = 0; i < 4; ++i)
#pragma unroll
                    for (int j = 0; j < 4; ++j) {
                        acc[i][j] = fmaf(va[i].x, vb[j].x, acc[i][j]);
                        acc[i][j] = fmaf(va[i].y, vb[j].y, acc[i][j]);
                        acc[i][j] = fmaf(va[i].z, vb[j].z, acc[i][j]);
                        acc[i][j] = fmaf(va[i].w, vb[j].w, acc[i][j]);
                    }
            }
        }
        // dist = cnorm - 2*dot (+||z||^2, common per row -> drop for argmin)
#pragma unroll
        for (int j = 0; j < 4; ++j) {
            const int code = kc + 4 * tx + j;
            const float cn = cnorm[code];
#pragma unroll
            for (int i = 0; i < 4; ++i) {
                const float d = fmaf(-2.0f, acc[i][j], cn);
                if (d < bestv[i]) { bestv[i] = d; besti[i] = code; }
            }
        }
    }

    // cross-tx argmin reduce (first-index tie-break), buf reused
    __syncthreads();
    float* minv = buf;                   // [64][16]
    int* mini = (int*)(buf + 1024);      // [64][16]
#pragma unroll
    for (int i = 0; i < 4; ++i) {
        minv[(4 * ty + i) * 16 + tx] = bestv[i];
        mini[(4 * ty + i) * 16 + tx] = besti[i];
    }
    __syncthreads();
    if (tid < 64) {
        float bv = minv[tid * 16];
        int bi = mini[tid * 16];
        for (int t = 1; t < 16; ++t) {
            const float v = minv[tid * 16 + t];
            const int ii = mini[tid * 16 + t];
            if (v < bv || (v == bv && ii < bi)) { bv = v; bi = ii; }
        }
        kbest[tid] = bi;
        out_code[rowBase + tid] = (float)bi;
    }
    if (tid == 0) blockSum = 0.0f;
    __syncthreads();

    // losses: sum_e (C[k*][e] - z[e])^2, 4 threads per row
    {
        const int r = tid >> 2, q = tid & 3;
        const int kr = kbest[r];
        const float* crow = cbook + (size_t)kr * 256 + q * 64;
        float s = 0.0f;
#pragma unroll
        for (int e = 0; e < 64; ++e) {
            const float d = crow[e] - zs[r][q * 64 + e];
            s = fmaf(d, d, s);
        }
        s += __shfl_down(s, 2);
        s += __shfl_down(s, 1);
        if (q == 0) atomicAdd(&blockSum, s);
    }
    __syncthreads();
    if (tid == 0) {
        const int b = rowBase >> 12;  // / 4096 rows per batch
        const float v = blockSum * (1.0f / (4096.0f * 256.0f));
        atomicAdd(&out_loss[b], v);        // commitment_loss
        atomicAdd(&out_loss[16 + b], v);   // codebook_loss (identical fwd)
    }
}

// ---------------- kernel 4: z_q = C[code] @ W_up^T (gathered GEMM) ----------
__global__ __launch_bounds__(256) void gemm_up_kernel(const float* __restrict__ cbook,
                                                      const float* __restrict__ code_f,
                                                      const float* __restrict__ Wup,
                                                      float* __restrict__ C) {
    __shared__ __align__(16) float As[64][36];
    __shared__ __align__(16) float Bs[64][36];
    __shared__ int ci[64];
    const int tid = threadIdx.x;
    const int tx = tid & 15, ty = tid >> 4;
    const int rowBase = blockIdx.x * 64;
    const int colBase = blockIdx.y * 64;
    if (tid < 64) ci[tid] = (int)code_f[rowBase + tid];
    __syncthreads();
    const int lr = tid >> 2;
    const int lk = (tid & 3) * 8;
    float acc[4][4] = {};
    for (int k0 = 0; k0 < 256; k0 += 32) {
        const float4 a0 = *(const float4*)(cbook + (size_t)ci[lr] * 256 + k0 + lk);
        const float4 a1 = *(const float4*)(cbook + (size_t)ci[lr] * 256 + k0 + lk + 4);
        const float4 b0 = *(const float4*)(Wup + (size_t)(colBase + lr) * 256 + k0 + lk);
        const float4 b1 = *(const float4*)(Wup + (size_t)(colBase + lr) * 256 + k0 + lk + 4);
        __syncthreads();
        *(float4*)&As[lr][lk] = a0;
        *(float4*)&As[lr][lk + 4] = a1;
        *(float4*)&Bs[lr][lk] = b0;
        *(float4*)&Bs[lr][lk + 4] = b1;
        __syncthreads();
#pragma unroll
        for (int e = 0; e < 32; e += 4) {
            float4 va[4], vb[4];
#pragma unroll
            for (int i = 0; i < 4; ++i) va[i] = *(const float4*)&As[4 * ty + i][e];
#pragma unroll
            for (int j = 0; j < 4; ++j) vb[j] = *(const float4*)&Bs[4 * tx + j][e];
#pragma unroll
            for (int i = 0; i < 4; ++i)
#pragma unroll
                for (int j = 0; j < 4; ++j) {
                    acc[i][j] = fmaf(va[i].x, vb[j].x, acc[i][j]);
                    acc[i][j] = fmaf(va[i].y, vb[j].y, acc[i][j]);
                    acc[i][j] = fmaf(va[i].z, vb[j].z, acc[i][j]);
                    acc[i][j] = fmaf(va[i].w, vb[j].w, acc[i][j]);
                }
        }
    }
#pragma unroll
    for (int i = 0; i < 4; ++i) {
        float4 o = make_float4(acc[i][0], acc[i][1], acc[i][2], acc[i][3]);
        *(float4*)(C + (size_t)(rowBase + 4 * ty + i) * 512 + colBase + 4 * tx) = o;
    }
}

extern "C" void kernel_launch(void* const* d_in, const int* in_sizes, int n_in,
                              void* d_out, int out_size, void* d_ws, size_t ws_size,
                              hipStream_t stream) {
    const float* z_e = (const float*)d_in[0];      // [16,4096,512]
    const float* cbook = (const float*)d_in[1];    // [1024,256]
    const float* W_down = (const float*)d_in[2];   // [256,512]
    const float* W_up = (const float*)d_in[3];     // [512,256]

    float* out = (float*)d_out;
    float* out_zq = out;                           // 33554432
    float* out_zed = out + 33554432;               // 16777216
    float* out_code = out_zed + 16777216;          // 65536
    float* out_loss = out_code + 65536;            // 32 (commit 16 + cb 16)

    float* cnorm = (float*)d_ws;                   // 1024 floats

    hipLaunchKernelGGL(cnorm_kernel, dim3(KC), dim3(256), 0, stream,
                       cbook, cnorm, out_loss);
    hipLaunchKernelGGL((gemm_rowdot<512, 256>), dim3(BT_TOTAL / 64, DEMB / 64), dim3(256),
                       0, stream, z_e, W_down, out_zed);
    hipLaunchKernelGGL(dist_argmin_kernel, dim3(BT_TOTAL / 64), dim3(256), 0, stream,
                       out_zed, cbook, cnorm, out_code, out_loss);
    hipLaunchKernelGGL(gemm_up_kernel, dim3(BT_TOTAL / 64, DIN / 64), dim3(256), 0, stream,
                       cbook, out_code, W_up, out_zq);
}

// Round 2
// 900.159 us; speedup vs baseline: 2.8282x; 2.8282x over previous
//
#include <hip/hip_runtime.h>
#include <math.h>

#define BT_TOTAL 65536
#define DIN 512
#define DEMB 256
#define KCODES 1024

typedef __attribute__((ext_vector_type(8))) short short8;
typedef __attribute__((ext_vector_type(4))) float floatx4;

__device__ __forceinline__ unsigned short f2bf(float x) {
    unsigned u = __float_as_uint(x);
    unsigned r = u + 0x7fffu + ((u >> 16) & 1u);
    return (unsigned short)(r >> 16);
}
__device__ __forceinline__ float bf2f(unsigned short h) {
    return __uint_as_float(((unsigned)h) << 16);
}

// ---------------- K0a: codebook row norms + zero loss outputs ---------------
__global__ __launch_bounds__(256) void cnorm_kernel(const float* __restrict__ cbook,
                                                    float* __restrict__ cnorm,
                                                    float* __restrict__ out_loss) {
    const int k = blockIdx.x;
    const int tid = threadIdx.x;
    float v = cbook[k * DEMB + tid];
    v *= v;
#pragma unroll
    for (int o = 32; o > 0; o >>= 1) v += __shfl_down(v, o);
    __shared__ float ps[4];
    if ((tid & 63) == 0) ps[tid >> 6] = v;
    __syncthreads();
    if (tid == 0) cnorm[k] = ps[0] + ps[1] + ps[2] + ps[3];
    if (k == 0 && tid < 32) out_loss[tid] = 0.0f;
}

// ---------------- K0b: split+swizzle [N][K] row-major matrix into -----------
// MFMA B-fragment order: offset(c,k) = (((c>>4)*(K/32) + (k>>5))*64 + lane)*8 + (k&7)
// with lane = ((k>>3)&3)*16 + (c&15). One thread per output element.
__global__ __launch_bounds__(256) void swz_kernel(const float* __restrict__ Bt,
                                                  unsigned short* __restrict__ hi,
                                                  unsigned short* __restrict__ lo,
                                                  int K, int total) {
    const int o = blockIdx.x * 256 + threadIdx.x;
    if (o >= total) return;
    const int j = o & 7;
    const int l = (o >> 3) & 63;
    const int r = o >> 9;
    const int kst = K >> 5;
    const int s = r % kst;
    const int t = r / kst;
    const int c = t * 16 + (l & 15);
    const int k = s * 32 + (l >> 4) * 8 + j;
    const float v = Bt[(size_t)c * K + k];
    const unsigned short h = f2bf(v);
    hi[o] = (unsigned short)h;
    lo[o] = f2bf(v - bf2f(h));
}

// ---------------- K1: z_e_down = z_e @ W_down^T  (MFMA bf16x2) --------------
// Wave-level: each wave owns 16 rows, sweeps all 256 output cols (16 tiles).
__global__ __launch_bounds__(256) void gemm_down_mfma(const float* __restrict__ A,
                                                      const unsigned short* __restrict__ bhi,
                                                      const unsigned short* __restrict__ blo,
                                                      float* __restrict__ C) {
    const int tid = threadIdx.x;
    const int lane = tid & 63, wv = tid >> 6;
    const int m = lane & 15, q = lane >> 4;
    const int rowBase = blockIdx.x * 64 + wv * 16;

    floatx4 acc[16];
#pragma unroll
    for (int t = 0; t < 16; ++t) acc[t] = (floatx4){0.f, 0.f, 0.f, 0.f};

    for (int s = 0; s < 16; ++s) {  // K = 512, chunks of 32
        const float4* ap = (const float4*)(A + (size_t)(rowBase + m) * DIN + s * 32 + q * 8);
        const float4 v0 = ap[0], v1 = ap[1];
        const float xs[8] = {v0.x, v0.y, v0.z, v0.w, v1.x, v1.y, v1.z, v1.w};
        short8 ahi, alo;
#pragma unroll
        for (int j = 0; j < 8; ++j) {
            const unsigned short h = f2bf(xs[j]);
            ahi[j] = (short)h;
            alo[j] = (short)f2bf(xs[j] - bf2f(h));
        }
#pragma unroll
        for (int t = 0; t < 16; ++t) {
            const size_t bo = ((size_t)(t * 16 + s) * 64 + lane) * 8;
            const short8 bh = *(const short8*)(bhi + bo);
            const short8 bl = *(const short8*)(blo + bo);
            acc[t] = __builtin_amdgcn_mfma_f32_16x16x32_bf16(ahi, bh, acc[t], 0, 0, 0);
            acc[t] = __builtin_amdgcn_mfma_f32_16x16x32_bf16(alo, bh, acc[t], 0, 0, 0);
            acc[t] = __builtin_amdgcn_mfma_f32_16x16x32_bf16(ahi, bl, acc[t], 0, 0, 0);
        }
    }
#pragma unroll
    for (int t = 0; t < 16; ++t)
#pragma unroll
        for (int r = 0; r < 4; ++r)
            C[(size_t)(rowBase + q * 4 + r) * DEMB + t * 16 + m] = acc[t][r];
}

// ---------------- K2: dist + argmin + losses (MFMA bf16x2) ------------------
// Wave owns 16 rows; A-frags register-resident across the 64 code tiles.
__global__ __launch_bounds__(256) void dist_mfma(const float* __restrict__ zed,
                                                 const unsigned short* __restrict__ chi,
                                                 const unsigned short* __restrict__ clo,
                                                 const float* __restrict__ cnorm,
                                                 float* __restrict__ out_code,
                                                 float* __restrict__ out_loss) {
    __shared__ float cn_s[KCODES];
    __shared__ float znorm_s[64];
    __shared__ float blockSum;
    const int tid = threadIdx.x;
    const int lane = tid & 63, wv = tid >> 6;
    const int m = lane & 15, q = lane >> 4;
    const int rowBase = blockIdx.x * 64 + wv * 16;

    *(float4*)&cn_s[tid * 4] = *(const float4*)(cnorm + tid * 4);
    if (tid == 0) blockSum = 0.f;

    // A fragments (hi/lo) for this wave's 16 rows, all K=256; plus row norms.
    short8 ahi[8], alo[8];
    float zn = 0.f;
#pragma unroll
    for (int s = 0; s < 8; ++s) {
        const float4* ap = (const float4*)(zed + (size_t)(rowBase + m) * DEMB + s * 32 + q * 8);
        const float4 v0 = ap[0], v1 = ap[1];
        const float xs[8] = {v0.x, v0.y, v0.z, v0.w, v1.x, v1.y, v1.z, v1.w};
#pragma unroll
        for (int j = 0; j < 8; ++j) {
            const unsigned short h = f2bf(xs[j]);
            ahi[s][j] = (short)h;
            alo[s][j] = (short)f2bf(xs[j] - bf2f(h));
            zn = fmaf(xs[j], xs[j], zn);
        }
    }
    zn += __shfl_xor(zn, 16, 64);
    zn += __shfl_xor(zn, 32, 64);
    if (q == 0) znorm_s[wv * 16 + m] = zn;
    __syncthreads();

    float bestv[4] = {INFINITY, INFINITY, INFINITY, INFINITY};
    int besti[4] = {0, 0, 0, 0};

    for (int t = 0; t < 64; ++t) {
        floatx4 acc0 = (floatx4){0.f, 0.f, 0.f, 0.f};
        floatx4 acc1 = (floatx4){0.f, 0.f, 0.f, 0.f};
#pragma unroll
        for (int s = 0; s < 8; s += 2) {
            const size_t b0 = ((size_t)(t * 8 + s) * 64 + lane) * 8;
            const size_t b1 = ((size_t)(t * 8 + s + 1) * 64 + lane) * 8;
            const short8 bh0 = *(const short8*)(chi + b0);
            const short8 bl0 = *(const short8*)(clo + b0);
            const short8 bh1 = *(const short8*)(chi + b1);
            const short8 bl1 = *(const short8*)(clo + b1);
            acc0 = __builtin_amdgcn_mfma_f32_16x16x32_bf16(ahi[s], bh0, acc0, 0, 0, 0);
            acc0 = __builtin_amdgcn_mfma_f32_16x16x32_bf16(alo[s], bh0, acc0, 0, 0, 0);
            acc0 = __builtin_amdgcn_mfma_f32_16x16x32_bf16(ahi[s], bl0, acc0, 0, 0, 0);
            acc1 = __builtin_amdgcn_mfma_f32_16x16x32_bf16(ahi[s + 1], bh1, acc1, 0, 0, 0);
            acc1 = __builtin_amdgcn_mfma_f32_16x16x32_bf16(alo[s + 1], bh1, acc1, 0, 0, 0);
            acc1 = __builtin_amdgcn_mfma_f32_16x16x32_bf16(ahi[s + 1], bl1, acc1, 0, 0, 0);
        }
        const int code = t * 16 + m;
        const float cn = cn_s[code];
#pragma unroll
        for (int r = 0; r < 4; ++r) {
            const float d = fmaf(-2.f, acc0[r] + acc1[r], cn);
            if (d < bestv[r]) { bestv[r] = d; besti[r] = code; }
        }
    }

    // reduce across the 16 lanes of each quad (first-index tie-break)
#pragma unroll
    for (int off = 1; off < 16; off <<= 1) {
#pragma unroll
        for (int r = 0; r < 4; ++r) {
            const float ov = __shfl_xor(bestv[r], off, 16);
            const int oi = __shfl_xor(besti[r], off, 16);
            if (ov < bestv[r] || (ov == bestv[r] && oi < besti[r])) {
                bestv[r] = ov;
                besti[r] = oi;
            }
        }
    }
    if (m == 0) {
        float ls = 0.f;
#pragma unroll
        for (int r = 0; r < 4; ++r) {
            const int lrow = q * 4 + r;
            out_code[rowBase + lrow] = (float)besti[r];
            ls += bestv[r] + znorm_s[wv * 16 + lrow];  // ||c-z||^2 = (cn-2dot)+||z||^2
        }
        atomicAdd(&blockSum, ls);
    }
    __syncthreads();
    if (tid == 0) {
        const int b = blockIdx.x >> 6;  // 64 blocks per batch
        const float v = blockSum * (1.0f / (4096.0f * 256.0f));
        atomicAdd(&out_loss[b], v);
        atomicAdd(&out_loss[16 + b], v);
    }
}

// ---------------- K3: z_q = C[code] @ W_up^T  (MFMA bf16x2, gathered A) -----
__global__ __launch_bounds__(256) void gemm_up_mfma(const unsigned short* __restrict__ chi,
                                                    const unsigned short* __restrict__ clo,
                                                    const float* __restrict__ code_f,
                                                    const unsigned short* __restrict__ whi,
                                                    const unsigned short* __restrict__ wlo,
                                                    float* __restrict__ C) {
    const int tid = threadIdx.x;
    const int lane = tid & 63, wv = tid >> 6;
    const int m = lane & 15, q = lane >> 4;
    const int rowBase = blockIdx.x * 64 + wv * 16;
    const int ci = (int)code_f[rowBase + m];

    for (int half = 0; half < 2; ++half) {
        floatx4 acc[16];
#pragma unroll
        for (int t = 0; t < 16; ++t) acc[t] = (floatx4){0.f, 0.f, 0.f, 0.f};
        for (int s = 0; s < 8; ++s) {  // K = 256
            const size_t ao = (((size_t)(ci >> 4) * 8 + s) * 64 + q * 16 + (ci & 15)) * 8;
            const short8 ah = *(const short8*)(chi + ao);
            const short8 al = *(const short8*)(clo + ao);
#pragma unroll
            for (int t = 0; t < 16; ++t) {
                const int gt = half * 16 + t;
                const size_t bo = ((size_t)(gt * 8 + s) * 64 + lane) * 8;
                const short8 bh = *(const short8*)(whi + bo);
                const short8 bl = *(const short8*)(wlo + bo);
                acc[t] = __builtin_amdgcn_mfma_f32_16x16x32_bf16(ah, bh, acc[t], 0, 0, 0);
                acc[t] = __builtin_amdgcn_mfma_f32_16x16x32_bf16(al, bh, acc[t], 0, 0, 0);
                acc[t] = __builtin_amdgcn_mfma_f32_16x16x32_bf16(ah, bl, acc[t], 0, 0, 0);
            }
        }
#pragma unroll
        for (int t = 0; t < 16; ++t)
#pragma unroll
            for (int r = 0; r < 4; ++r)
                C[(size_t)(rowBase + q * 4 + r) * DIN + half * 256 + t * 16 + m] = acc[t][r];
    }
}

extern "C" void kernel_launch(void* const* d_in, const int* in_sizes, int n_in,
                              void* d_out, int out_size, void* d_ws, size_t ws_size,
                              hipStream_t stream) {
    const float* z_e = (const float*)d_in[0];      // [16,4096,512]
    const float* cbook = (const float*)d_in[1];    // [1024,256]
    const float* W_down = (const float*)d_in[2];   // [256,512]
    const float* W_up = (const float*)d_in[3];     // [512,256]

    float* out = (float*)d_out;
    float* out_zq = out;                           // 33554432
    float* out_zed = out + 33554432;               // 16777216
    float* out_code = out_zed + 16777216;          // 65536
    float* out_loss = out_code + 65536;            // 32

    // ws layout (bytes): cnorm 4K | cb_hi 512K | cb_lo 512K | wd_hi 256K |
    //                    wd_lo 256K | wu_hi 256K | wu_lo 256K  (total ~2.05 MB)
    char* wsb = (char*)d_ws;
    float* cnorm = (float*)wsb;
    unsigned short* cb_hi = (unsigned short*)(wsb + 4096);
    unsigned short* cb_lo = (unsigned short*)(wsb + 4096 + 524288);
    unsigned short* wd_hi = (unsigned short*)(wsb + 4096 + 2 * 524288);
    unsigned short* wd_lo = (unsigned short*)(wsb + 4096 + 2 * 524288 + 262144);
    unsigned short* wu_hi = (unsigned short*)(wsb + 4096 + 2 * 524288 + 2 * 262144);
    unsigned short* wu_lo = (unsigned short*)(wsb + 4096 + 2 * 524288 + 3 * 262144);

    cnorm_kernel<<<KCODES, 256, 0, stream>>>(cbook, cnorm, out_loss);
    swz_kernel<<<1024, 256, 0, stream>>>(cbook, cb_hi, cb_lo, 256, 262144);
    swz_kernel<<<512, 256, 0, stream>>>(W_down, wd_hi, wd_lo, 512, 131072);
    swz_kernel<<<512, 256, 0, stream>>>(W_up, wu_hi, wu_lo, 256, 131072);

    gemm_down_mfma<<<BT_TOTAL / 64, 256, 0, stream>>>(z_e, wd_hi, wd_lo, out_zed);
    dist_mfma<<<BT_TOTAL / 64, 256, 0, stream>>>(out_zed, cb_hi, cb_lo, cnorm,
                                                 out_code, out_loss);
    gemm_up_mfma<<<BT_TOTAL / 64, 256, 0, stream>>>(cb_hi, cb_lo, out_code,
                                                    wu_hi, wu_lo, out_zq);
}

// Round 3
// 512.031 us; speedup vs baseline: 4.9720x; 1.7580x over previous
//
#include <hip/hip_runtime.h>
#include <math.h>

#define BT_TOTAL 65536
#define DIN 512
#define DEMB 256
#define KCODES 1024

typedef __attribute__((ext_vector_type(8))) short short8;
typedef __attribute__((ext_vector_type(4))) float floatx4;

__device__ __forceinline__ unsigned short f2bf(float x) {
    unsigned u = __float_as_uint(x);
    unsigned r = u + 0x7fffu + ((u >> 16) & 1u);
    return (unsigned short)(r >> 16);
}
__device__ __forceinline__ float bf2f(unsigned short h) {
    return __uint_as_float(((unsigned)h) << 16);
}

// ---------------- K0a: codebook row norms + zero loss outputs ---------------
__global__ __launch_bounds__(256) void cnorm_kernel(const float* __restrict__ cbook,
                                                    float* __restrict__ cnorm,
                                                    float* __restrict__ out_loss) {
    const int k = blockIdx.x;
    const int tid = threadIdx.x;
    float v = cbook[k * DEMB + tid];
    v *= v;
#pragma unroll
    for (int o = 32; o > 0; o >>= 1) v += __shfl_down(v, o);
    __shared__ float ps[4];
    if ((tid & 63) == 0) ps[tid >> 6] = v;
    __syncthreads();
    if (tid == 0) cnorm[k] = ps[0] + ps[1] + ps[2] + ps[3];
    if (k == 0 && tid < 32) out_loss[tid] = 0.0f;
}

// ---------------- K0b: split+swizzle [N][K] row-major into MFMA B-frag order
// offset(c,k) = (((c>>4)*(K/32) + (k>>5))*64 + lane)*8 + (k&7),
// lane = ((k>>3)&3)*16 + (c&15).
__global__ __launch_bounds__(256) void swz_kernel(const float* __restrict__ Bt,
                                                  unsigned short* __restrict__ hi,
                                                  unsigned short* __restrict__ lo,
                                                  int K, int total) {
    const int o = blockIdx.x * 256 + threadIdx.x;
    if (o >= total) return;
    const int j = o & 7;
    const int l = (o >> 3) & 63;
    const int r = o >> 9;
    const int kst = K >> 5;
    const int s = r % kst;
    const int t = r / kst;
    const int c = t * 16 + (l & 15);
    const int k = s * 32 + (l >> 4) * 8 + j;
    const float v = Bt[(size_t)c * K + k];
    const unsigned short h = f2bf(v);
    hi[o] = (unsigned short)h;
    lo[o] = f2bf(v - bf2f(h));
}

// ---------------- fp32 VALU GEMM (for tiny P-matrix): C = A * Bt^T ----------
template <int KD, int NSTR>
__global__ __launch_bounds__(256) void gemm_rowdot(const float* __restrict__ A,
                                                   const float* __restrict__ Bt,
                                                   float* __restrict__ C) {
    __shared__ __align__(16) float As[64][36];
    __shared__ __align__(16) float Bs[64][36];
    const int tid = threadIdx.x;
    const int tx = tid & 15, ty = tid >> 4;
    const int rowBase = blockIdx.x * 64;
    const int colBase = blockIdx.y * 64;
    const int lr = tid >> 2;
    const int lk = (tid & 3) * 8;
    float acc[4][4] = {};
    for (int k0 = 0; k0 < KD; k0 += 32) {
        const float4 a0 = *(const float4*)(A + (size_t)(rowBase + lr) * KD + k0 + lk);
        const float4 a1 = *(const float4*)(A + (size_t)(rowBase + lr) * KD + k0 + lk + 4);
        const float4 b0 = *(const float4*)(Bt + (size_t)(colBase + lr) * KD + k0 + lk);
        const float4 b1 = *(const float4*)(Bt + (size_t)(colBase + lr) * KD + k0 + lk + 4);
        __syncthreads();
        *(float4*)&As[lr][lk] = a0;
        *(float4*)&As[lr][lk + 4] = a1;
        *(float4*)&Bs[lr][lk] = b0;
        *(float4*)&Bs[lr][lk + 4] = b1;
        __syncthreads();
#pragma unroll
        for (int e = 0; e < 32; e += 4) {
            float4 va[4], vb[4];
#pragma unroll
            for (int i = 0; i < 4; ++i) va[i] = *(const float4*)&As[4 * ty + i][e];
#pragma unroll
            for (int j = 0; j < 4; ++j) vb[j] = *(const float4*)&Bs[4 * tx + j][e];
#pragma unroll
            for (int i = 0; i < 4; ++i)
#pragma unroll
                for (int j = 0; j < 4; ++j) {
                    acc[i][j] = fmaf(va[i].x, vb[j].x, acc[i][j]);
                    acc[i][j] = fmaf(va[i].y, vb[j].y, acc[i][j]);
                    acc[i][j] = fmaf(va[i].z, vb[j].z, acc[i][j]);
                    acc[i][j] = fmaf(va[i].w, vb[j].w, acc[i][j]);
                }
        }
    }
#pragma unroll
    for (int i = 0; i < 4; ++i) {
        float4 o = make_float4(acc[i][0], acc[i][1], acc[i][2], acc[i][3]);
        *(float4*)(C + (size_t)(rowBase + 4 * ty + i) * NSTR + colBase + 4 * tx) = o;
    }
}

// ---------------- K1: z_e_down = z_e @ W_down^T  (MFMA bf16x2, LDS-staged B)
__global__ __launch_bounds__(256) void gemm_down_mfma(const float* __restrict__ A,
                                                      const unsigned short* __restrict__ bhi,
                                                      const unsigned short* __restrict__ blo,
                                                      float* __restrict__ C) {
    __shared__ __align__(16) short lds_h[16][512];  // [t][lane*8] for current s
    __shared__ __align__(16) short lds_l[16][512];
    const int tid = threadIdx.x;
    const int lane = tid & 63, wv = tid >> 6;
    const int m = lane & 15, q = lane >> 4;
    const int rowBase = blockIdx.x * 64 + wv * 16;

    floatx4 acc[16];
#pragma unroll
    for (int t = 0; t < 16; ++t) acc[t] = (floatx4){0.f, 0.f, 0.f, 0.f};

    for (int s = 0; s < 16; ++s) {  // K = 512, chunks of 32
        // A chunk for this wave's rows (global, overlaps barrier wait)
        const float4* ap = (const float4*)(A + (size_t)(rowBase + m) * DIN + s * 32 + q * 8);
        const float4 v0 = ap[0], v1 = ap[1];
        __syncthreads();  // previous-iteration LDS reads done
        // stage B fragments for this s: 32 chunks of 1 KB over 4 waves
#pragma unroll
        for (int i = 0; i < 8; ++i) {
            const int c = wv * 8 + i;
            const int t = c >> 1;
            const unsigned short* src = (c & 1) ? blo : bhi;
            const short8 vst = *(const short8*)(src + ((size_t)(t * 16 + s) * 64 + lane) * 8);
            short* dst = (c & 1) ? &lds_l[t][lane * 8] : &lds_h[t][lane * 8];
            *(short8*)dst = vst;
        }
        // convert A to hi/lo fragments
        const float xs[8] = {v0.x, v0.y, v0.z, v0.w, v1.x, v1.y, v1.z, v1.w};
        short8 ahi, alo;
#pragma unroll
        for (int j = 0; j < 8; ++j) {
            const unsigned short h = f2bf(xs[j]);
            ahi[j] = (short)h;
            alo[j] = (short)f2bf(xs[j] - bf2f(h));
        }
        __syncthreads();
#pragma unroll
        for (int t = 0; t < 16; ++t) {
            const short8 bh = *(const short8*)&lds_h[t][lane * 8];
            const short8 bl = *(const short8*)&lds_l[t][lane * 8];
            acc[t] = __builtin_amdgcn_mfma_f32_16x16x32_bf16(ahi, bh, acc[t], 0, 0, 0);
            acc[t] = __builtin_amdgcn_mfma_f32_16x16x32_bf16(alo, bh, acc[t], 0, 0, 0);
            acc[t] = __builtin_amdgcn_mfma_f32_16x16x32_bf16(ahi, bl, acc[t], 0, 0, 0);
        }
    }
#pragma unroll
    for (int t = 0; t < 16; ++t)
#pragma unroll
        for (int r = 0; r < 4; ++r)
            C[(size_t)(rowBase + q * 4 + r) * DEMB + t * 16 + m] = acc[t][r];
}

// ---------------- K2: dist + argmin + losses (MFMA bf16x2, LDS-staged B) ----
__global__ __launch_bounds__(256) void dist_mfma(const float* __restrict__ zed,
                                                 const unsigned short* __restrict__ chi,
                                                 const unsigned short* __restrict__ clo,
                                                 const float* __restrict__ cnorm,
                                                 float* __restrict__ out_code,
                                                 float* __restrict__ out_loss) {
    __shared__ __align__(16) short lds_h[2][8][512];  // [buf][s][lane*8]
    __shared__ __align__(16) short lds_l[2][8][512];
    __shared__ float cn_s[KCODES];
    __shared__ float znorm_s[64];
    __shared__ float blockSum;
    const int tid = threadIdx.x;
    const int lane = tid & 63, wv = tid >> 6;
    const int m = lane & 15, q = lane >> 4;
    const int rowBase = blockIdx.x * 64 + wv * 16;

    *(float4*)&cn_s[tid * 4] = *(const float4*)(cnorm + tid * 4);
    if (tid == 0) blockSum = 0.f;

    // A fragments (hi/lo) for this wave's 16 rows, all K=256; plus row norms.
    short8 ahi[8], alo[8];
    float zn = 0.f;
#pragma unroll
    for (int s = 0; s < 8; ++s) {
        const float4* ap = (const float4*)(zed + (size_t)(rowBase + m) * DEMB + s * 32 + q * 8);
        const float4 v0 = ap[0], v1 = ap[1];
        const float xs[8] = {v0.x, v0.y, v0.z, v0.w, v1.x, v1.y, v1.z, v1.w};
#pragma unroll
        for (int j = 0; j < 8; ++j) {
            const unsigned short h = f2bf(xs[j]);
            ahi[s][j] = (short)h;
            alo[s][j] = (short)f2bf(xs[j] - bf2f(h));
            zn = fmaf(xs[j], xs[j], zn);
        }
    }
    zn += __shfl_xor(zn, 16, 64);
    zn += __shfl_xor(zn, 32, 64);
    if (q == 0) znorm_s[wv * 16 + m] = zn;

    // stage tile 0 into buf 0: 16 chunks of 1 KB over 4 waves
#pragma unroll
    for (int i = 0; i < 4; ++i) {
        const int c = wv * 4 + i;
        const int s = c >> 1;
        const unsigned short* src = (c & 1) ? clo : chi;
        const short8 vst = *(const short8*)(src + ((size_t)(0 * 8 + s) * 64 + lane) * 8);
        short* dst = (c & 1) ? &lds_l[0][s][lane * 8] : &lds_h[0][s][lane * 8];
        *(short8*)dst = vst;
    }
    __syncthreads();

    float bestv[4] = {INFINITY, INFINITY, INFINITY, INFINITY};
    int besti[4] = {0, 0, 0, 0};
    int buf = 0;

    for (int t = 0; t < 64; ++t) {
        if (t < 63) {  // prefetch next tile into other buffer
#pragma unroll
            for (int i = 0; i < 4; ++i) {
                const int c = wv * 4 + i;
                const int s = c >> 1;
                const unsigned short* src = (c & 1) ? clo : chi;
                const short8 vst =
                    *(const short8*)(src + ((size_t)((t + 1) * 8 + s) * 64 + lane) * 8);
                short* dst = (c & 1) ? &lds_l[buf ^ 1][s][lane * 8]
                                     : &lds_h[buf ^ 1][s][lane * 8];
                *(short8*)dst = vst;
            }
        }
        floatx4 acc0 = (floatx4){0.f, 0.f, 0.f, 0.f};
        floatx4 acc1 = (floatx4){0.f, 0.f, 0.f, 0.f};
#pragma unroll
        for (int s = 0; s < 8; s += 2) {
            const short8 bh0 = *(const short8*)&lds_h[buf][s][lane * 8];
            const short8 bl0 = *(const short8*)&lds_l[buf][s][lane * 8];
            const short8 bh1 = *(const short8*)&lds_h[buf][s + 1][lane * 8];
            const short8 bl1 = *(const short8*)&lds_l[buf][s + 1][lane * 8];
            acc0 = __builtin_amdgcn_mfma_f32_16x16x32_bf16(ahi[s], bh0, acc0, 0, 0, 0);
            acc0 = __builtin_amdgcn_mfma_f32_16x16x32_bf16(alo[s], bh0, acc0, 0, 0, 0);
            acc0 = __builtin_amdgcn_mfma_f32_16x16x32_bf16(ahi[s], bl0, acc0, 0, 0, 0);
            acc1 = __builtin_amdgcn_mfma_f32_16x16x32_bf16(ahi[s + 1], bh1, acc1, 0, 0, 0);
            acc1 = __builtin_amdgcn_mfma_f32_16x16x32_bf16(alo[s + 1], bh1, acc1, 0, 0, 0);
            acc1 = __builtin_amdgcn_mfma_f32_16x16x32_bf16(ahi[s + 1], bl1, acc1, 0, 0, 0);
        }
        const int code = t * 16 + m;
        const float cn = cn_s[code];
#pragma unroll
        for (int r = 0; r < 4; ++r) {
            const float d = fmaf(-2.f, acc0[r] + acc1[r], cn);
            if (d < bestv[r]) { bestv[r] = d; besti[r] = code; }
        }
        __syncthreads();  // next buffer staged; current buffer reads done
        buf ^= 1;
    }

    // reduce across the 16 lanes of each quad (first-index tie-break)
#pragma unroll
    for (int off = 1; off < 16; off <<= 1) {
#pragma unroll
        for (int r = 0; r < 4; ++r) {
            const float ov = __shfl_xor(bestv[r], off, 16);
            const int oi = __shfl_xor(besti[r], off, 16);
            if (ov < bestv[r] || (ov == bestv[r] && oi < besti[r])) {
                bestv[r] = ov;
                besti[r] = oi;
            }
        }
    }
    if (m == 0) {
        float ls = 0.f;
#pragma unroll
        for (int r = 0; r < 4; ++r) {
            const int lrow = q * 4 + r;
            out_code[rowBase + lrow] = (float)besti[r];
            ls += bestv[r] + znorm_s[wv * 16 + lrow];  // ||c-z||^2
        }
        atomicAdd(&blockSum, ls);
    }
    __syncthreads();
    if (tid == 0) {
        const int b = blockIdx.x >> 6;  // 64 blocks per batch
        const float v = blockSum * (1.0f / (4096.0f * 256.0f));
        atomicAdd(&out_loss[b], v);
        atomicAdd(&out_loss[16 + b], v);
    }
}

// ---------------- K4: z_q[row] = P[code[row]]  (pure gather-copy) -----------
__global__ __launch_bounds__(256) void gather_kernel(const float* __restrict__ P,
                                                     const float* __restrict__ code_f,
                                                     float* __restrict__ zq) {
    const int lane = threadIdx.x & 63;
    const int row = blockIdx.x * 4 + (threadIdx.x >> 6);
    const int c = (int)code_f[row];
    const float4* src = (const float4*)(P + (size_t)c * DIN);
    float4* dst = (float4*)(zq + (size_t)row * DIN);
    dst[lane] = src[lane];
    dst[lane + 64] = src[lane + 64];
}

extern "C" void kernel_launch(void* const* d_in, const int* in_sizes, int n_in,
                              void* d_out, int out_size, void* d_ws, size_t ws_size,
                              hipStream_t stream) {
    const float* z_e = (const float*)d_in[0];      // [16,4096,512]
    const float* cbook = (const float*)d_in[1];    // [1024,256]
    const float* W_down = (const float*)d_in[2];   // [256,512]
    const float* W_up = (const float*)d_in[3];     // [512,256]

    float* out = (float*)d_out;
    float* out_zq = out;                           // 33554432
    float* out_zed = out + 33554432;               // 16777216
    float* out_code = out_zed + 16777216;          // 65536
    float* out_loss = out_code + 65536;            // 32

    // ws: [0,4K) cnorm | [4K, 4K+1.5M) swizzles | P (2 MB) overlays swizzles
    // after dist (peak 2101248 B — identical to round-2 footprint).
    char* wsb = (char*)d_ws;
    float* cnorm = (float*)wsb;
    unsigned short* cb_hi = (unsigned short*)(wsb + 4096);
    unsigned short* cb_lo = (unsigned short*)(wsb + 4096 + 524288);
    unsigned short* wd_hi = (unsigned short*)(wsb + 4096 + 2 * 524288);
    unsigned short* wd_lo = (unsigned short*)(wsb + 4096 + 2 * 524288 + 262144);
    float* P = (float*)(wsb + 4096);               // [1024][512]

    cnorm_kernel<<<KCODES, 256, 0, stream>>>(cbook, cnorm, out_loss);
    swz_kernel<<<1024, 256, 0, stream>>>(cbook, cb_hi, cb_lo, 256, 262144);
    swz_kernel<<<512, 256, 0, stream>>>(W_down, wd_hi, wd_lo, 512, 131072);

    gemm_down_mfma<<<BT_TOTAL / 64, 256, 0, stream>>>(z_e, wd_hi, wd_lo, out_zed);
    dist_mfma<<<BT_TOTAL / 64, 256, 0, stream>>>(out_zed, cb_hi, cb_lo, cnorm,
                                                 out_code, out_loss);
    // P = cbook @ W_up^T (fp32 VALU; overwrites swizzle area, now dead)
    gemm_rowdot<256, 512><<<dim3(16, 8), 256, 0, stream>>>(cbook, W_up, P);
    gather_kernel<<<BT_TOTAL / 4, 256, 0, stream>>>(P, out_code, out_zq);
}